// Round 8
// baseline (343.894 us; speedup 1.0000x reference)
//
#include <hip/hip_runtime.h>

// Problem constants
#define NB 8
#define NC 128
#define NH 64
#define NW 64
#define HEADS 4
#define HP 32
#define WP 32
#define NTOK 1024     // HP*WP
#define TOPK 32
#define HDIM 32

typedef float v2f __attribute__((ext_vector_type(2)));

// ---------------------------------------------------------------
// bf16 helpers (round-to-nearest-even)
__device__ __forceinline__ unsigned bf16r(float f) {
  unsigned u = __float_as_uint(f);
  return (u + 0x7FFFu + ((u >> 16) & 1u)) >> 16;
}

// monotone float->uint map (order-preserving) and inverse
__device__ __forceinline__ unsigned fmap(float f) {
  unsigned u = __float_as_uint(f);
  return u ^ ((unsigned)((int)u >> 31) | 0x80000000u);
}
__device__ __forceinline__ float funmap(unsigned k) {
  unsigned uo = k ^ ((unsigned)((int)(~k) >> 31) | 0x80000000u);
  return __uint_as_float(uo);
}

__device__ __forceinline__ v2f bfpair(unsigned w) {
  v2f r;
  r.x = __uint_as_float(w << 16);
  r.y = __uint_as_float(w & 0xFFFF0000u);
  return r;
}

// DPP wave64 max-reduce on unsigned; result broadcast via readlane(63)
__device__ __forceinline__ unsigned wave_maxu(unsigned v) {
#define ST(ctrl)                                                                     \
  {                                                                                  \
    unsigned o = (unsigned)__builtin_amdgcn_update_dpp(0, (int)v, ctrl, 0xF, 0xF, true); \
    v = v > o ? v : o;                                                               \
  }
  ST(0xB1)   // quad_perm [1,0,3,2]
  ST(0x4E)   // quad_perm [2,3,0,1]
  ST(0x141)  // row_half_mirror
  ST(0x140)  // row_mirror
  ST(0x142)  // row_bcast:15
  ST(0x143)  // row_bcast:31
#undef ST
  return (unsigned)__builtin_amdgcn_readlane((int)v, 63);
}

// DPP wave64 float sum-reduce; result broadcast via readlane(63)
__device__ __forceinline__ float wave_sumf(float v) {
#define STA(ctrl)                                                                    \
  v += __int_as_float(__builtin_amdgcn_update_dpp(0, __float_as_int(v), ctrl, 0xF, 0xF, true));
  STA(0xB1)
  STA(0x4E)
  STA(0x141)
  STA(0x140)
  STA(0x142)
  STA(0x143)
#undef STA
  return __int_as_float(__builtin_amdgcn_readlane(__float_as_int(v), 63));
}

// DPP wave64 inclusive prefix-sum on unsigned (row_shr within 16-rows, then
// masked adds of row totals). Safe for packed 16+16-bit fields (sums < 2^16).
__device__ __forceinline__ unsigned wave_iprefix(unsigned v, int lane) {
#define SH(ctrl)                                                                     \
  v += (unsigned)__builtin_amdgcn_update_dpp(0, (int)v, ctrl, 0xF, 0xF, true);
  SH(0x111)  // row_shr:1
  SH(0x112)  // row_shr:2
  SH(0x114)  // row_shr:4
  SH(0x118)  // row_shr:8
#undef SH
  unsigned r0 = (unsigned)__builtin_amdgcn_readlane((int)v, 15);
  unsigned r1 = (unsigned)__builtin_amdgcn_readlane((int)v, 31);
  unsigned r2 = (unsigned)__builtin_amdgcn_readlane((int)v, 47);
  v += (lane >= 16) ? r0 : 0u;
  v += (lane >= 32) ? r1 : 0u;
  v += (lane >= 48) ? r2 : 0u;
  return v;
}

// ---------------------------------------------------------------
// avg pool 2x2 on x and y
__global__ void k_pool(const float* __restrict__ x, const float* __restrict__ y,
                       float* __restrict__ xp, float* __restrict__ yp) {
  int idx = blockIdx.x * 256 + threadIdx.x;
  const int total = NB * NC * HP * WP; // 1,048,576
  if (idx >= 2 * total) return;
  bool isY = idx >= total;
  int i = isY ? idx - total : idx;
  int pw = i & 31, ph = (i >> 5) & 31, bc = i >> 10;
  const float* src = (isY ? y : x) + ((size_t)bc * 64 + ph * 2) * 64 + pw * 2;
  float v = 0.25f * (src[0] + src[1] + src[64] + src[65]);
  (isY ? yp : xp)[i] = v;
}

// ---------------------------------------------------------------
// 1x1 conv, 16 outputs per thread (weights wave-uniform -> s_loads)
template <int CO>
__global__ void k_conv1x1(const float* __restrict__ in, const float* __restrict__ wt,
                          const float* __restrict__ bias, float* __restrict__ out) {
  const int CG = CO / 16;
  int p = (blockIdx.x & 3) * 256 + threadIdx.x;
  int rest = blockIdx.x >> 2;
  int cg = rest % CG;
  int b = rest / CG;
  if (b >= NB) return;
  const float* ip = in + (size_t)b * NC * NTOK + p;
  const float* wp = wt + cg * 16 * NC;
  float acc[16];
#pragma unroll
  for (int i = 0; i < 16; i++) acc[i] = bias[cg * 16 + i];
  for (int ci = 0; ci < NC; ci++) {
    float mv = ip[ci * NTOK];
#pragma unroll
    for (int i = 0; i < 16; i++) acc[i] = fmaf(wp[i * NC + ci], mv, acc[i]);
  }
#pragma unroll
  for (int i = 0; i < 16; i++) out[((size_t)b * CO + cg * 16 + i) * NTOK + p] = acc[i];
}

// ---------------------------------------------------------------
// depthwise 3x3 pad=1 on (B,128,32,32)
__global__ void k_dw3(const float* __restrict__ in, const float* __restrict__ wt,
                      const float* __restrict__ bias, float* __restrict__ out) {
  int t = blockIdx.x * 256 + threadIdx.x;
  if (t >= NB * NC * NTOK) return;
  int p = t & 1023;
  int pw = p & 31, ph = p >> 5;
  int bc = t >> 10;
  int c = bc & 127;
  const float* ip = in + (size_t)bc * NTOK;
  const float* wp = wt + c * 9;
  float acc = bias[c];
#pragma unroll
  for (int ky = 0; ky < 3; ky++) {
    int ih = ph + ky - 1;
    if (ih < 0 || ih > 31) continue;
#pragma unroll
    for (int kx = 0; kx < 3; kx++) {
      int iw = pw + kx - 1;
      if (iw < 0 || iw > 31) continue;
      acc = fmaf(wp[ky * 3 + kx], ip[ih * 32 + iw], acc);
    }
  }
  out[t] = acc;
}

// ---------------------------------------------------------------
// grouped 3x3 (groups=128) on kv1 (B,256,32,32); emits bf16 K and bf16 V
__global__ void k_kv2(const float* __restrict__ in, const float* __restrict__ wt,
                      const float* __restrict__ bias, unsigned short* __restrict__ kbf,
                      unsigned short* __restrict__ vbf) {
  int t = blockIdx.x * 256 + threadIdx.x;
  if (t >= NB * 256 * NTOK) return;
  int p = t & 1023;
  int pw = p & 31, ph = p >> 5;
  int bo = t >> 10;
  int o = bo & 255;
  int b = bo >> 8;
  int g = o >> 1;
  const float* ip0 = in + ((size_t)b * 256 + 2 * g) * NTOK;
  const float* ip1 = ip0 + NTOK;
  const float* wp = wt + o * 18; // [2][3][3]
  float acc = bias[o];
#pragma unroll
  for (int ky = 0; ky < 3; ky++) {
    int ih = ph + ky - 1;
    if (ih < 0 || ih > 31) continue;
#pragma unroll
    for (int kx = 0; kx < 3; kx++) {
      int iw = pw + kx - 1;
      if (iw < 0 || iw > 31) continue;
      float w0 = wp[ky * 3 + kx];
      float w1 = wp[9 + ky * 3 + kx];
      acc = fmaf(w0, ip0[ih * 32 + iw], acc);
      acc = fmaf(w1, ip1[ih * 32 + iw], acc);
    }
  }
  unsigned short bv = (unsigned short)bf16r(acc);
  if (o < 128) {
    kbf[((size_t)b * NC + o) * NTOK + p] = bv;
  } else {
    int c = o - 128;
    int h = c >> 5, d = c & 31;
    vbf[(((size_t)b * HEADS + h) * NTOK + p) * HDIM + d] = bv;
  }
}

// ---------------------------------------------------------------
// attention v6: top-32 via wave-cooperative binary search on the rank-32
// threshold (ballot+popcount counting), exact tie handling via prefix sums,
// LDS compaction, then parallel softmax + pipelined V gather.
// grid: 512 = 16 chunks x 4 h x 8 b; block 1024 (16 waves), 4 rows per wave.
__launch_bounds__(1024, 4)
__global__ void k_attn(const float* __restrict__ qbuf, const unsigned short* __restrict__ kbf,
                       const unsigned short* __restrict__ vbf, const float* __restrict__ rel,
                       const float* __restrict__ temp, float* __restrict__ att) {
  __shared__ __align__(16) unsigned ksh[16384];   // bf16 K [d][n], 64KB
  __shared__ __align__(16) unsigned cbuf[16 * 64]; // per-wave 32x(key,token), 4KB

  int bid = blockIdx.x;
  int chunk = bid & 15;
  int h = (bid >> 4) & 3;
  int b = bid >> 6;
  int tid = threadIdx.x;
  int lane = tid & 63;
  int wave = __builtin_amdgcn_readfirstlane(tid >> 6); // 0..15, uniform

  // stage K (already bf16 in global): 8192 uint2 total, 1024 threads x 8
  const uint2* kg = (const uint2*)(kbf + ((size_t)b * NC + h * HDIM) * NTOK);
  uint2* kl = (uint2*)ksh;
#pragma unroll
  for (int i = 0; i < 8; i++) kl[tid + i * 1024] = kg[tid + i * 1024];
  __syncthreads();

  const float tmpr = temp[h];
  const float invt = 1.0f / tmpr;
  const uint2* k2 = (const uint2*)ksh;
  const unsigned short* vb = vbf + ((size_t)(b * HEADS + h)) * NTOK * HDIM;
  int vlane = lane & 31;
  unsigned* row_lds = cbuf + wave * 64; // 32 entries x 8B, private per wave

  int qbase = chunk * 64 + wave * 4;

  // acc init = rel * (1/t)
  v2f acc2[4][8];
  {
    const float4* relp = (const float4*)(rel + (((size_t)b * HEADS + h) * NTOK + qbase) * NTOK);
#pragma unroll
    for (int r = 0; r < 4; r++) {
#pragma unroll
      for (int i = 0; i < 4; i++) {
        float4 rv = relp[r * 256 + i * 64 + lane];
        v2f a0; a0.x = rv.x * invt; a0.y = rv.y * invt;
        v2f a1; a1.x = rv.z * invt; a1.y = rv.w * invt;
        acc2[r][i * 2 + 0] = a0;
        acc2[r][i * 2 + 1] = a1;
      }
    }
  }

  // logits: acc += q_d * K[d][j]
  const float* q0 = qbuf + ((size_t)b * NC + h * HDIM) * NTOK + qbase;
#pragma unroll 4
  for (int d = 0; d < 32; d++) {
    float4 qv = *(const float4*)&q0[d * NTOK];
#pragma unroll
    for (int i = 0; i < 4; i++) {
      uint2 kw = k2[d * 256 + i * 64 + lane];
      v2f klo = bfpair(kw.x);
      v2f khi = bfpair(kw.y);
      v2f q0s = {qv.x, qv.x}, q1s = {qv.y, qv.y}, q2s = {qv.z, qv.z}, q3s = {qv.w, qv.w};
      acc2[0][i * 2 + 0] = __builtin_elementwise_fma(q0s, klo, acc2[0][i * 2 + 0]);
      acc2[0][i * 2 + 1] = __builtin_elementwise_fma(q0s, khi, acc2[0][i * 2 + 1]);
      acc2[1][i * 2 + 0] = __builtin_elementwise_fma(q1s, klo, acc2[1][i * 2 + 0]);
      acc2[1][i * 2 + 1] = __builtin_elementwise_fma(q1s, khi, acc2[1][i * 2 + 1]);
      acc2[2][i * 2 + 0] = __builtin_elementwise_fma(q2s, klo, acc2[2][i * 2 + 0]);
      acc2[2][i * 2 + 1] = __builtin_elementwise_fma(q2s, khi, acc2[2][i * 2 + 1]);
      acc2[3][i * 2 + 0] = __builtin_elementwise_fma(q3s, klo, acc2[3][i * 2 + 0]);
      acc2[3][i * 2 + 1] = __builtin_elementwise_fma(q3s, khi, acc2[3][i * 2 + 1]);
    }
  }

  // per-row: keys -> threshold bsearch -> compact -> softmax+gather
#pragma unroll 1
  for (int r = 0; r < 4; r++) {
    // full-precision monotone keys; element e -> token (e>>2)*256 + lane*4 + (e&3)
    unsigned k[16];
#pragma unroll
    for (int j = 0; j < 8; j++) {
      k[2 * j + 0] = fmap(tmpr * acc2[r][j].x);
      k[2 * j + 1] = fmap(tmpr * acc2[r][j].y);
    }

    // wave max (for bsearch upper bound + softmax max)
    unsigned mx = k[0];
#pragma unroll
    for (int e = 1; e < 16; e++) mx = mx > k[e] ? mx : k[e];
    unsigned M = wave_maxu(mx);

    // binary search: smallest T with count(key > T) < 32  (T = 32nd largest key)
    unsigned lo = 0u, hi = M;
#pragma unroll 1
    for (int it = 0; it < 32; it++) {
      unsigned mid = lo + ((hi - lo) >> 1);
      int cnt = 0;
#pragma unroll
      for (int e = 0; e < 16; e++) cnt += (int)__popcll(__ballot(k[e] > mid));
      if (cnt >= TOPK) lo = mid; else hi = mid;
    }
    unsigned T = hi;

    // per-lane counts: gtc = #{> T}, tq = #{== T}
    unsigned gtc = 0, tq = 0;
#pragma unroll
    for (int e = 0; e < 16; e++) {
      gtc += (k[e] > T) ? 1u : 0u;
      tq += (k[e] == T) ? 1u : 0u;
    }
    // fused prefix over packed (gtc | tq<<16)
    unsigned packed = gtc | (tq << 16);
    unsigned incl = wave_iprefix(packed, lane);
    unsigned tot = (unsigned)__builtin_amdgcn_readlane((int)incl, 63);
    unsigned n_gt = tot & 0xFFFFu;
    unsigned tie_pfx = (incl >> 16) - tq;
    unsigned extras = (unsigned)TOPK - n_gt; // >= 1 by construction
    int el = (int)extras - (int)tie_pfx;
    el = el < 0 ? 0 : el;
    el = el > (int)tq ? (int)tq : el;
    unsigned sc = gtc + (unsigned)el;
    unsigned wbase = wave_iprefix(sc, lane) - sc;

    // compaction: write selected (key, token) pairs to per-wave LDS strip
    unsigned wp = wbase, tr = tie_pfx;
#pragma unroll
    for (int e = 0; e < 16; e++) {
      bool gt = k[e] > T;
      bool eq = (k[e] == T);
      bool take = gt || (eq && (tr < extras));
      tr += eq ? 1u : 0u;
      if (take) {
        ((uint2*)row_lds)[wp] = make_uint2(k[e], (unsigned)((e >> 2) * 256 + lane * 4 + (e & 3)));
        wp++;
      }
    }

    // parallel softmax over the 32 entries (lanes 0..31) + pipelined V gather
    uint2 ent = ((const uint2*)row_lds)[vlane];
    float fv = funmap(ent.x);
    float mv = funmap(M);
    float e_ = __expf(fv - mv);
    e_ = (lane < TOPK) ? e_ : 0.f;
    float se = wave_sumf(e_);

    float oacc = 0.f;
#pragma unroll
    for (int t = 0; t < TOPK; t++) {
      float es = __int_as_float(__builtin_amdgcn_readlane(__float_as_int(e_), t));
      int tok = __builtin_amdgcn_readlane((int)ent.y, t);
      float vv = __uint_as_float((unsigned)vb[(size_t)tok * HDIM + vlane] << 16);
      oacc = fmaf(es, vv, oacc);
    }

    if (lane < HDIM) {
      att[((size_t)b * NC + h * HDIM + lane) * NTOK + (qbase + r)] = oacc / se;
    }
  }
}

// ---------------------------------------------------------------
// bilinear 2x upsample weights (jax scale_and_translate semantics)
__device__ __forceinline__ void bil(int i, int& j0, int& j1, float& wa, float& wb) {
  if (i & 1) {
    j0 = i >> 1; j1 = j0 + 1; wa = 0.75f; wb = 0.25f;
    if (j1 > 31) { j1 = 31; wa = 1.f; wb = 0.f; }
  } else {
    j0 = (i >> 1) - 1; j1 = j0 + 1; wa = 0.25f; wb = 0.75f;
    if (j0 < 0) { j0 = 0; wa = 0.f; wb = 1.f; }
  }
}

// mid = lepe(x) + upsample(att) ; (B,128,64,64)
__global__ void k_mid(const float* __restrict__ x, const float* __restrict__ lepe_w,
                      const float* __restrict__ lepe_b, const float* __restrict__ att,
                      float* __restrict__ mid) {
  int t = blockIdx.x * 256 + threadIdx.x;
  if (t >= NB * NC * NH * NW) return;
  int w = t & 63;
  int h0 = (t >> 6) & 63;
  int bc = t >> 12;
  int c = bc & 127;
  const float* xp = x + (size_t)bc * (NH * NW);
  const float* wp = lepe_w + c * 25;
  float acc = lepe_b[c];
#pragma unroll
  for (int ky = 0; ky < 5; ky++) {
    int ih = h0 + ky - 2;
    if (ih < 0 || ih > 63) continue;
#pragma unroll
    for (int kx = 0; kx < 5; kx++) {
      int iw = w + kx - 2;
      if (iw < 0 || iw > 63) continue;
      acc = fmaf(wp[ky * 5 + kx], xp[ih * 64 + iw], acc);
    }
  }
  int jh0, jh1, jw0, jw1;
  float wha, whb, wwa, wwb;
  bil(h0, jh0, jh1, wha, whb);
  bil(w, jw0, jw1, wwa, wwb);
  const float* ap = att + (size_t)bc * NTOK;
  float up = wha * (wwa * ap[jh0 * 32 + jw0] + wwb * ap[jh0 * 32 + jw1]) +
             whb * (wwa * ap[jh1 * 32 + jw0] + wwb * ap[jh1 * 32 + jw1]);
  mid[t] = acc + up;
}

// ---------------------------------------------------------------
// final 1x1 conv, 32 outputs per thread (mid re-read 4x instead of 16x)
__global__ void k_final(const float* __restrict__ mid, const float* __restrict__ wt,
                        const float* __restrict__ bias, float* __restrict__ out) {
  int p = (blockIdx.x & 15) * 256 + threadIdx.x;
  int rest = blockIdx.x >> 4;
  int cg = rest & 3;
  int b = rest >> 2;
  if (b >= NB) return;
  const float* mp = mid + (size_t)b * NC * (NH * NW) + p;
  const float* wp = wt + cg * 32 * NC;
  float acc[32];
#pragma unroll
  for (int i = 0; i < 32; i++) acc[i] = bias[cg * 32 + i];
  for (int ci = 0; ci < NC; ci++) {
    float mv = mp[ci * 4096];
#pragma unroll
    for (int i = 0; i < 32; i++) acc[i] = fmaf(wp[i * NC + ci], mv, acc[i]);
  }
#pragma unroll
  for (int i = 0; i < 32; i++) out[((size_t)b * NC + cg * 32 + i) * 4096 + p] = acc[i];
}

// ---------------------------------------------------------------
extern "C" void kernel_launch(void* const* d_in, const int* in_sizes, int n_in,
                              void* d_out, int out_size, void* d_ws, size_t ws_size,
                              hipStream_t stream) {
  const float* x      = (const float*)d_in[0];
  const float* y      = (const float*)d_in[1];
  const float* rel    = (const float*)d_in[2];
  const float* q1_w   = (const float*)d_in[3];
  const float* q1_b   = (const float*)d_in[4];
  const float* q2_w   = (const float*)d_in[5];
  const float* q2_b   = (const float*)d_in[6];
  const float* kv1_w  = (const float*)d_in[7];
  const float* kv1_b  = (const float*)d_in[8];
  const float* kv2_w  = (const float*)d_in[9];
  const float* kv2_b  = (const float*)d_in[10];
  const float* lepe_w = (const float*)d_in[11];
  const float* lepe_b = (const float*)d_in[12];
  const float* out_w  = (const float*)d_in[13];
  const float* out_b  = (const float*)d_in[14];
  const float* temp   = (const float*)d_in[15];
  float* out = (float*)d_out;

  float* ws = (float*)d_ws;
  const size_t SP = (size_t)NB * NC * NTOK;   // 1,048,576
  float* xp     = ws;                  // SP
  float* yp     = xp + SP;             // SP
  float* q1buf  = yp + SP;             // SP
  float* kv1buf = q1buf + SP;          // 2*SP
  float* qbuf   = kv1buf + 2 * SP;     // SP
  float* attb   = qbuf + SP;           // SP
  float* mid    = attb + SP;           // 4*SP
  unsigned short* kbf = (unsigned short*)(mid + 4 * SP);  // SP ushorts (2MB)
  unsigned short* vbf = kbf + SP;                         // SP ushorts (2MB)

  k_pool<<<8192, 256, 0, stream>>>(x, y, xp, yp);
  k_conv1x1<128><<<256, 256, 0, stream>>>(xp, q1_w, q1_b, q1buf);
  k_dw3<<<4096, 256, 0, stream>>>(q1buf, q2_w, q2_b, qbuf);
  k_conv1x1<256><<<512, 256, 0, stream>>>(yp, kv1_w, kv1_b, kv1buf);
  k_kv2<<<8192, 256, 0, stream>>>(kv1buf, kv2_w, kv2_b, kbf, vbf);
  k_attn<<<512, 1024, 0, stream>>>(qbuf, kbf, vbf, rel, temp, attb);
  k_mid<<<16384, 256, 0, stream>>>(x, lepe_w, lepe_b, attb, mid);
  k_final<<<512, 256, 0, stream>>>(mid, out_w, out_b, out);
}

// Round 9
// 304.085 us; speedup vs baseline: 1.1309x; 1.1309x over previous
//
#include <hip/hip_runtime.h>

// Problem constants
#define NB 8
#define NC 128
#define NH 64
#define NW 64
#define HEADS 4
#define HP 32
#define WP 32
#define NTOK 1024     // HP*WP
#define TOPK 32
#define HDIM 32

typedef float v2f __attribute__((ext_vector_type(2)));

// ---------------------------------------------------------------
// bf16 helpers (round-to-nearest-even)
__device__ __forceinline__ unsigned bf16r(float f) {
  unsigned u = __float_as_uint(f);
  return (u + 0x7FFFu + ((u >> 16) & 1u)) >> 16;
}

// monotone float->uint map (order-preserving) and inverse
__device__ __forceinline__ unsigned fmap(float f) {
  unsigned u = __float_as_uint(f);
  return u ^ ((unsigned)((int)u >> 31) | 0x80000000u);
}
__device__ __forceinline__ float funmap(unsigned k) {
  unsigned uo = k ^ ((unsigned)((int)(~k) >> 31) | 0x80000000u);
  return __uint_as_float(uo);
}

__device__ __forceinline__ v2f bfpair(unsigned w) {
  v2f r;
  r.x = __uint_as_float(w << 16);
  r.y = __uint_as_float(w & 0xFFFF0000u);
  return r;
}

// DPP wave64 max-reduce on unsigned; result broadcast via readlane(63)
__device__ __forceinline__ unsigned wave_maxu(unsigned v) {
#define ST(ctrl)                                                                     \
  {                                                                                  \
    unsigned o = (unsigned)__builtin_amdgcn_update_dpp(0, (int)v, ctrl, 0xF, 0xF, true); \
    v = v > o ? v : o;                                                               \
  }
  ST(0xB1)   // quad_perm [1,0,3,2]
  ST(0x4E)   // quad_perm [2,3,0,1]
  ST(0x141)  // row_half_mirror
  ST(0x140)  // row_mirror
  ST(0x142)  // row_bcast:15
  ST(0x143)  // row_bcast:31
#undef ST
  return (unsigned)__builtin_amdgcn_readlane((int)v, 63);
}

// DPP wave64 float sum-reduce; result broadcast via readlane(63)
__device__ __forceinline__ float wave_sumf(float v) {
#define STA(ctrl)                                                                    \
  v += __int_as_float(__builtin_amdgcn_update_dpp(0, __float_as_int(v), ctrl, 0xF, 0xF, true));
  STA(0xB1)
  STA(0x4E)
  STA(0x141)
  STA(0x140)
  STA(0x142)
  STA(0x143)
#undef STA
  return __int_as_float(__builtin_amdgcn_readlane(__float_as_int(v), 63));
}

// DPP wave64 inclusive prefix-sum on unsigned. Safe for packed 16+16 fields.
__device__ __forceinline__ unsigned wave_iprefix(unsigned v, int lane) {
#define SH(ctrl)                                                                     \
  v += (unsigned)__builtin_amdgcn_update_dpp(0, (int)v, ctrl, 0xF, 0xF, true);
  SH(0x111)  // row_shr:1
  SH(0x112)  // row_shr:2
  SH(0x114)  // row_shr:4
  SH(0x118)  // row_shr:8
#undef SH
  unsigned r0 = (unsigned)__builtin_amdgcn_readlane((int)v, 15);
  unsigned r1 = (unsigned)__builtin_amdgcn_readlane((int)v, 31);
  unsigned r2 = (unsigned)__builtin_amdgcn_readlane((int)v, 47);
  v += (lane >= 16) ? r0 : 0u;
  v += (lane >= 32) ? r1 : 0u;
  v += (lane >= 48) ? r2 : 0u;
  return v;
}

// ---------------------------------------------------------------
// avg pool 2x2 on x and y
__global__ void k_pool(const float* __restrict__ x, const float* __restrict__ y,
                       float* __restrict__ xp, float* __restrict__ yp) {
  int idx = blockIdx.x * 256 + threadIdx.x;
  const int total = NB * NC * HP * WP; // 1,048,576
  if (idx >= 2 * total) return;
  bool isY = idx >= total;
  int i = isY ? idx - total : idx;
  int pw = i & 31, ph = (i >> 5) & 31, bc = i >> 10;
  const float* src = (isY ? y : x) + ((size_t)bc * 64 + ph * 2) * 64 + pw * 2;
  float v = 0.25f * (src[0] + src[1] + src[64] + src[65]);
  (isY ? yp : xp)[i] = v;
}

// ---------------------------------------------------------------
// 1x1 conv, 16 outputs per thread (weights wave-uniform -> s_loads)
template <int CO>
__global__ void k_conv1x1(const float* __restrict__ in, const float* __restrict__ wt,
                          const float* __restrict__ bias, float* __restrict__ out) {
  const int CG = CO / 16;
  int p = (blockIdx.x & 3) * 256 + threadIdx.x;
  int rest = blockIdx.x >> 2;
  int cg = rest % CG;
  int b = rest / CG;
  if (b >= NB) return;
  const float* ip = in + (size_t)b * NC * NTOK + p;
  const float* wp = wt + cg * 16 * NC;
  float acc[16];
#pragma unroll
  for (int i = 0; i < 16; i++) acc[i] = bias[cg * 16 + i];
  for (int ci = 0; ci < NC; ci++) {
    float mv = ip[ci * NTOK];
#pragma unroll
    for (int i = 0; i < 16; i++) acc[i] = fmaf(wp[i * NC + ci], mv, acc[i]);
  }
#pragma unroll
  for (int i = 0; i < 16; i++) out[((size_t)b * CO + cg * 16 + i) * NTOK + p] = acc[i];
}

// ---------------------------------------------------------------
// depthwise 3x3 pad=1 on (B,128,32,32)
__global__ void k_dw3(const float* __restrict__ in, const float* __restrict__ wt,
                      const float* __restrict__ bias, float* __restrict__ out) {
  int t = blockIdx.x * 256 + threadIdx.x;
  if (t >= NB * NC * NTOK) return;
  int p = t & 1023;
  int pw = p & 31, ph = p >> 5;
  int bc = t >> 10;
  int c = bc & 127;
  const float* ip = in + (size_t)bc * NTOK;
  const float* wp = wt + c * 9;
  float acc = bias[c];
#pragma unroll
  for (int ky = 0; ky < 3; ky++) {
    int ih = ph + ky - 1;
    if (ih < 0 || ih > 31) continue;
#pragma unroll
    for (int kx = 0; kx < 3; kx++) {
      int iw = pw + kx - 1;
      if (iw < 0 || iw > 31) continue;
      acc = fmaf(wp[ky * 3 + kx], ip[ih * 32 + iw], acc);
    }
  }
  out[t] = acc;
}

// ---------------------------------------------------------------
// grouped 3x3 (groups=128) on kv1 (B,256,32,32); emits bf16 K and bf16 V
__global__ void k_kv2(const float* __restrict__ in, const float* __restrict__ wt,
                      const float* __restrict__ bias, unsigned short* __restrict__ kbf,
                      unsigned short* __restrict__ vbf) {
  int t = blockIdx.x * 256 + threadIdx.x;
  if (t >= NB * 256 * NTOK) return;
  int p = t & 1023;
  int pw = p & 31, ph = p >> 5;
  int bo = t >> 10;
  int o = bo & 255;
  int b = bo >> 8;
  int g = o >> 1;
  const float* ip0 = in + ((size_t)b * 256 + 2 * g) * NTOK;
  const float* ip1 = ip0 + NTOK;
  const float* wp = wt + o * 18; // [2][3][3]
  float acc = bias[o];
#pragma unroll
  for (int ky = 0; ky < 3; ky++) {
    int ih = ph + ky - 1;
    if (ih < 0 || ih > 31) continue;
#pragma unroll
    for (int kx = 0; kx < 3; kx++) {
      int iw = pw + kx - 1;
      if (iw < 0 || iw > 31) continue;
      float w0 = wp[ky * 3 + kx];
      float w1 = wp[9 + ky * 3 + kx];
      acc = fmaf(w0, ip0[ih * 32 + iw], acc);
      acc = fmaf(w1, ip1[ih * 32 + iw], acc);
    }
  }
  unsigned short bv = (unsigned short)bf16r(acc);
  if (o < 128) {
    kbf[((size_t)b * NC + o) * NTOK + p] = bv;
  } else {
    int c = o - 128;
    int h = c >> 5, d = c & 31;
    vbf[(((size_t)b * HEADS + h) * NTOK + p) * HDIM + d] = bv;
  }
}

// ---------------------------------------------------------------
// attention v7: bsearch top-32 select with ALL per-row state statically
// indexed (2 rows per wave, fully interleaved/unrolled -> no scratch).
// grid: 2048 = 64 chunks x 4 h x 8 b; block 512 (8 waves), 2 rows per wave.
__launch_bounds__(512, 2)
__global__ void k_attn(const float* __restrict__ qbuf, const unsigned short* __restrict__ kbf,
                       const unsigned short* __restrict__ vbf, const float* __restrict__ rel,
                       const float* __restrict__ temp, float* __restrict__ att) {
  __shared__ __align__(16) unsigned ksh[16384];  // bf16 K [d][n], 64KB
  __shared__ __align__(16) unsigned cbuf[8 * 64]; // per-wave 32x(key,token), 2KB

  int bid = blockIdx.x;
  int chunk = bid & 63;
  int h = (bid >> 6) & 3;
  int b = bid >> 8;
  int tid = threadIdx.x;
  int lane = tid & 63;
  int wave = __builtin_amdgcn_readfirstlane(tid >> 6); // 0..7, uniform

  // stage K (already bf16 in global): 8192 uint2 total, 512 threads x 16
  const uint2* kg = (const uint2*)(kbf + ((size_t)b * NC + h * HDIM) * NTOK);
  uint2* kl = (uint2*)ksh;
#pragma unroll
  for (int i = 0; i < 16; i++) kl[tid + i * 512] = kg[tid + i * 512];
  __syncthreads();

  const float tmpr = temp[h];
  const float invt = 1.0f / tmpr;
  const uint2* k2 = (const uint2*)ksh;
  const unsigned short* vb = vbf + ((size_t)(b * HEADS + h)) * NTOK * HDIM;
  int vlane = lane & 31;
  unsigned* row_lds = cbuf + wave * 64; // 32 entries x 8B, private per wave

  int qbase = chunk * 16 + wave * 2;

  // acc init = rel * (1/t)
  v2f acc2[2][8];
  {
    const float4* relp = (const float4*)(rel + (((size_t)b * HEADS + h) * NTOK + qbase) * NTOK);
#pragma unroll
    for (int r = 0; r < 2; r++) {
#pragma unroll
      for (int i = 0; i < 4; i++) {
        float4 rv = relp[r * 256 + i * 64 + lane];
        v2f a0; a0.x = rv.x * invt; a0.y = rv.y * invt;
        v2f a1; a1.x = rv.z * invt; a1.y = rv.w * invt;
        acc2[r][i * 2 + 0] = a0;
        acc2[r][i * 2 + 1] = a1;
      }
    }
  }

  // logits: acc += q_d * K[d][j]
  const float* q0 = qbuf + ((size_t)b * NC + h * HDIM) * NTOK + qbase;
#pragma unroll 4
  for (int d = 0; d < 32; d++) {
    float2 qv = *(const float2*)&q0[d * NTOK];
#pragma unroll
    for (int i = 0; i < 4; i++) {
      uint2 kw = k2[d * 256 + i * 64 + lane];
      v2f klo = bfpair(kw.x);
      v2f khi = bfpair(kw.y);
      v2f q0s = {qv.x, qv.x}, q1s = {qv.y, qv.y};
      acc2[0][i * 2 + 0] = __builtin_elementwise_fma(q0s, klo, acc2[0][i * 2 + 0]);
      acc2[0][i * 2 + 1] = __builtin_elementwise_fma(q0s, khi, acc2[0][i * 2 + 1]);
      acc2[1][i * 2 + 0] = __builtin_elementwise_fma(q1s, klo, acc2[1][i * 2 + 0]);
      acc2[1][i * 2 + 1] = __builtin_elementwise_fma(q1s, khi, acc2[1][i * 2 + 1]);
    }
  }

  // full-precision monotone keys, statically indexed
  unsigned kk[2][16];
#pragma unroll
  for (int r = 0; r < 2; r++) {
#pragma unroll
    for (int j = 0; j < 8; j++) {
      kk[r][2 * j + 0] = fmap(tmpr * acc2[r][j].x);
      kk[r][2 * j + 1] = fmap(tmpr * acc2[r][j].y);
    }
  }

  // wave max per row (bsearch upper bound + softmax max)
  unsigned M[2];
#pragma unroll
  for (int r = 0; r < 2; r++) {
    unsigned mx = kk[r][0];
#pragma unroll
    for (int e = 1; e < 16; e++) mx = mx > kk[r][e] ? mx : kk[r][e];
    M[r] = wave_maxu(mx);
  }

  // interleaved binary search: smallest T with count(key > T) < 32
  unsigned lo0 = 0u, hi0 = M[0], lo1 = 0u, hi1 = M[1];
#pragma unroll 1
  for (int it = 0; it < 32; it++) {
    unsigned mid0 = lo0 + ((hi0 - lo0) >> 1);
    unsigned mid1 = lo1 + ((hi1 - lo1) >> 1);
    int c0 = 0, c1 = 0;
#pragma unroll
    for (int e = 0; e < 16; e++) {
      c0 += (int)__popcll(__ballot(kk[0][e] > mid0));
      c1 += (int)__popcll(__ballot(kk[1][e] > mid1));
    }
    if (c0 >= TOPK) lo0 = mid0; else hi0 = mid0;
    if (c1 >= TOPK) lo1 = mid1; else hi1 = mid1;
  }
  unsigned T[2] = {hi0, hi1};

  // per-row: tie handling, compaction, softmax + V gather (r unrolled -> static)
#pragma unroll
  for (int r = 0; r < 2; r++) {
    unsigned gtc = 0, tq = 0;
#pragma unroll
    for (int e = 0; e < 16; e++) {
      gtc += (kk[r][e] > T[r]) ? 1u : 0u;
      tq += (kk[r][e] == T[r]) ? 1u : 0u;
    }
    unsigned packed = gtc | (tq << 16);
    unsigned incl = wave_iprefix(packed, lane);
    unsigned tot = (unsigned)__builtin_amdgcn_readlane((int)incl, 63);
    unsigned n_gt = tot & 0xFFFFu;
    unsigned tie_pfx = (incl >> 16) - tq;
    unsigned extras = (unsigned)TOPK - n_gt; // >= 1 by construction
    int el = (int)extras - (int)tie_pfx;
    el = el < 0 ? 0 : el;
    el = el > (int)tq ? (int)tq : el;
    unsigned sc = gtc + (unsigned)el;
    unsigned wbase = wave_iprefix(sc, lane) - sc;

    unsigned wp = wbase, tr = tie_pfx;
#pragma unroll
    for (int e = 0; e < 16; e++) {
      bool gt = kk[r][e] > T[r];
      bool eq = (kk[r][e] == T[r]);
      bool take = gt || (eq && (tr < extras));
      tr += eq ? 1u : 0u;
      if (take) {
        ((uint2*)row_lds)[wp] = make_uint2(kk[r][e], (unsigned)((e >> 2) * 256 + lane * 4 + (e & 3)));
        wp++;
      }
    }

    // parallel softmax over the 32 entries (lanes 0..31) + pipelined V gather
    uint2 ent = ((const uint2*)row_lds)[vlane];
    float fv = funmap(ent.x);
    float mv = funmap(M[r]);
    float e_ = __expf(fv - mv);
    e_ = (lane < TOPK) ? e_ : 0.f;
    float se = wave_sumf(e_);

    float oacc = 0.f;
#pragma unroll
    for (int t = 0; t < TOPK; t++) {
      float es = __int_as_float(__builtin_amdgcn_readlane(__float_as_int(e_), t));
      int tok = __builtin_amdgcn_readlane((int)ent.y, t);
      float vv = __uint_as_float((unsigned)vb[(size_t)tok * HDIM + vlane] << 16);
      oacc = fmaf(es, vv, oacc);
    }

    if (lane < HDIM) {
      att[((size_t)b * NC + h * HDIM + lane) * NTOK + (qbase + r)] = oacc / se;
    }
  }
}

// ---------------------------------------------------------------
// bilinear 2x upsample weights (jax scale_and_translate semantics)
__device__ __forceinline__ void bil(int i, int& j0, int& j1, float& wa, float& wb) {
  if (i & 1) {
    j0 = i >> 1; j1 = j0 + 1; wa = 0.75f; wb = 0.25f;
    if (j1 > 31) { j1 = 31; wa = 1.f; wb = 0.f; }
  } else {
    j0 = (i >> 1) - 1; j1 = j0 + 1; wa = 0.25f; wb = 0.75f;
    if (j0 < 0) { j0 = 0; wa = 0.f; wb = 1.f; }
  }
}

// mid = lepe(x) + upsample(att) ; (B,128,64,64)
__global__ void k_mid(const float* __restrict__ x, const float* __restrict__ lepe_w,
                      const float* __restrict__ lepe_b, const float* __restrict__ att,
                      float* __restrict__ mid) {
  int t = blockIdx.x * 256 + threadIdx.x;
  if (t >= NB * NC * NH * NW) return;
  int w = t & 63;
  int h0 = (t >> 6) & 63;
  int bc = t >> 12;
  int c = bc & 127;
  const float* xp = x + (size_t)bc * (NH * NW);
  const float* wp = lepe_w + c * 25;
  float acc = lepe_b[c];
#pragma unroll
  for (int ky = 0; ky < 5; ky++) {
    int ih = h0 + ky - 2;
    if (ih < 0 || ih > 63) continue;
#pragma unroll
    for (int kx = 0; kx < 5; kx++) {
      int iw = w + kx - 2;
      if (iw < 0 || iw > 63) continue;
      acc = fmaf(wp[ky * 5 + kx], xp[ih * 64 + iw], acc);
    }
  }
  int jh0, jh1, jw0, jw1;
  float wha, whb, wwa, wwb;
  bil(h0, jh0, jh1, wha, whb);
  bil(w, jw0, jw1, wwa, wwb);
  const float* ap = att + (size_t)bc * NTOK;
  float up = wha * (wwa * ap[jh0 * 32 + jw0] + wwb * ap[jh0 * 32 + jw1]) +
             whb * (wwa * ap[jh1 * 32 + jw0] + wwb * ap[jh1 * 32 + jw1]);
  mid[t] = acc + up;
}

// ---------------------------------------------------------------
// final 1x1 conv, 32 outputs per thread (mid re-read 4x instead of 16x)
__global__ void k_final(const float* __restrict__ mid, const float* __restrict__ wt,
                        const float* __restrict__ bias, float* __restrict__ out) {
  int p = (blockIdx.x & 15) * 256 + threadIdx.x;
  int rest = blockIdx.x >> 4;
  int cg = rest & 3;
  int b = rest >> 2;
  if (b >= NB) return;
  const float* mp = mid + (size_t)b * NC * (NH * NW) + p;
  const float* wp = wt + cg * 32 * NC;
  float acc[32];
#pragma unroll
  for (int i = 0; i < 32; i++) acc[i] = bias[cg * 32 + i];
  for (int ci = 0; ci < NC; ci++) {
    float mv = mp[ci * 4096];
#pragma unroll
    for (int i = 0; i < 32; i++) acc[i] = fmaf(wp[i * NC + ci], mv, acc[i]);
  }
#pragma unroll
  for (int i = 0; i < 32; i++) out[((size_t)b * NC + cg * 32 + i) * 4096 + p] = acc[i];
}

// ---------------------------------------------------------------
extern "C" void kernel_launch(void* const* d_in, const int* in_sizes, int n_in,
                              void* d_out, int out_size, void* d_ws, size_t ws_size,
                              hipStream_t stream) {
  const float* x      = (const float*)d_in[0];
  const float* y      = (const float*)d_in[1];
  const float* rel    = (const float*)d_in[2];
  const float* q1_w   = (const float*)d_in[3];
  const float* q1_b   = (const float*)d_in[4];
  const float* q2_w   = (const float*)d_in[5];
  const float* q2_b   = (const float*)d_in[6];
  const float* kv1_w  = (const float*)d_in[7];
  const float* kv1_b  = (const float*)d_in[8];
  const float* kv2_w  = (const float*)d_in[9];
  const float* kv2_b  = (const float*)d_in[10];
  const float* lepe_w = (const float*)d_in[11];
  const float* lepe_b = (const float*)d_in[12];
  const float* out_w  = (const float*)d_in[13];
  const float* out_b  = (const float*)d_in[14];
  const float* temp   = (const float*)d_in[15];
  float* out = (float*)d_out;

  float* ws = (float*)d_ws;
  const size_t SP = (size_t)NB * NC * NTOK;   // 1,048,576
  float* xp     = ws;                  // SP
  float* yp     = xp + SP;             // SP
  float* q1buf  = yp + SP;             // SP
  float* kv1buf = q1buf + SP;          // 2*SP
  float* qbuf   = kv1buf + 2 * SP;     // SP
  float* attb   = qbuf + SP;           // SP
  float* mid    = attb + SP;           // 4*SP
  unsigned short* kbf = (unsigned short*)(mid + 4 * SP);  // SP ushorts (2MB)
  unsigned short* vbf = kbf + SP;                         // SP ushorts (2MB)

  k_pool<<<8192, 256, 0, stream>>>(x, y, xp, yp);
  k_conv1x1<128><<<256, 256, 0, stream>>>(xp, q1_w, q1_b, q1buf);
  k_dw3<<<4096, 256, 0, stream>>>(q1buf, q2_w, q2_b, qbuf);
  k_conv1x1<256><<<512, 256, 0, stream>>>(yp, kv1_w, kv1_b, kv1buf);
  k_kv2<<<8192, 256, 0, stream>>>(kv1buf, kv2_w, kv2_b, kbf, vbf);
  k_attn<<<2048, 512, 0, stream>>>(qbuf, kbf, vbf, rel, temp, attb);
  k_mid<<<16384, 256, 0, stream>>>(x, lepe_w, lepe_b, attb, mid);
  k_final<<<512, 256, 0, stream>>>(mid, out_w, out_b, out);
}

// Round 10
// 298.930 us; speedup vs baseline: 1.1504x; 1.0172x over previous
//
#include <hip/hip_runtime.h>

// Problem constants
#define NB 8
#define NC 128
#define NH 64
#define NW 64
#define HEADS 4
#define HP 32
#define WP 32
#define NTOK 1024     // HP*WP
#define TOPK 32
#define HDIM 32

typedef float v2f __attribute__((ext_vector_type(2)));

// ---------------------------------------------------------------
// bf16 helpers (round-to-nearest-even)
__device__ __forceinline__ unsigned bf16r(float f) {
  unsigned u = __float_as_uint(f);
  return (u + 0x7FFFu + ((u >> 16) & 1u)) >> 16;
}

// monotone float->uint map (order-preserving) and inverse
__device__ __forceinline__ unsigned fmap(float f) {
  unsigned u = __float_as_uint(f);
  return u ^ ((unsigned)((int)u >> 31) | 0x80000000u);
}
__device__ __forceinline__ float funmap(unsigned k) {
  unsigned uo = k ^ ((unsigned)((int)(~k) >> 31) | 0x80000000u);
  return __uint_as_float(uo);
}

__device__ __forceinline__ v2f bfpair(unsigned w) {
  v2f r;
  r.x = __uint_as_float(w << 16);
  r.y = __uint_as_float(w & 0xFFFF0000u);
  return r;
}

// DPP wave64 max-reduce on unsigned; result broadcast via readlane(63)
__device__ __forceinline__ unsigned wave_maxu(unsigned v) {
#define ST(ctrl)                                                                     \
  {                                                                                  \
    unsigned o = (unsigned)__builtin_amdgcn_update_dpp(0, (int)v, ctrl, 0xF, 0xF, true); \
    v = v > o ? v : o;                                                               \
  }
  ST(0xB1)   // quad_perm [1,0,3,2]
  ST(0x4E)   // quad_perm [2,3,0,1]
  ST(0x141)  // row_half_mirror
  ST(0x140)  // row_mirror
  ST(0x142)  // row_bcast:15
  ST(0x143)  // row_bcast:31
#undef ST
  return (unsigned)__builtin_amdgcn_readlane((int)v, 63);
}

// DPP wave64 float sum-reduce; result broadcast via readlane(63)
__device__ __forceinline__ float wave_sumf(float v) {
#define STA(ctrl)                                                                    \
  v += __int_as_float(__builtin_amdgcn_update_dpp(0, __float_as_int(v), ctrl, 0xF, 0xF, true));
  STA(0xB1)
  STA(0x4E)
  STA(0x141)
  STA(0x140)
  STA(0x142)
  STA(0x143)
#undef STA
  return __int_as_float(__builtin_amdgcn_readlane(__float_as_int(v), 63));
}

// DPP wave64 inclusive prefix-sum on unsigned. Safe for packed 16+16 fields.
__device__ __forceinline__ unsigned wave_iprefix(unsigned v, int lane) {
#define SH(ctrl)                                                                     \
  v += (unsigned)__builtin_amdgcn_update_dpp(0, (int)v, ctrl, 0xF, 0xF, true);
  SH(0x111)  // row_shr:1
  SH(0x112)  // row_shr:2
  SH(0x114)  // row_shr:4
  SH(0x118)  // row_shr:8
#undef SH
  unsigned r0 = (unsigned)__builtin_amdgcn_readlane((int)v, 15);
  unsigned r1 = (unsigned)__builtin_amdgcn_readlane((int)v, 31);
  unsigned r2 = (unsigned)__builtin_amdgcn_readlane((int)v, 47);
  v += (lane >= 16) ? r0 : 0u;
  v += (lane >= 32) ? r1 : 0u;
  v += (lane >= 48) ? r2 : 0u;
  return v;
}

// ---------------------------------------------------------------
// avg pool 2x2 on x and y
__global__ void k_pool(const float* __restrict__ x, const float* __restrict__ y,
                       float* __restrict__ xp, float* __restrict__ yp) {
  int idx = blockIdx.x * 256 + threadIdx.x;
  const int total = NB * NC * HP * WP; // 1,048,576
  if (idx >= 2 * total) return;
  bool isY = idx >= total;
  int i = isY ? idx - total : idx;
  int pw = i & 31, ph = (i >> 5) & 31, bc = i >> 10;
  const float* src = (isY ? y : x) + ((size_t)bc * 64 + ph * 2) * 64 + pw * 2;
  float v = 0.25f * (src[0] + src[1] + src[64] + src[65]);
  (isY ? yp : xp)[i] = v;
}

// ---------------------------------------------------------------
// 1x1 conv, 16 outputs per thread (weights wave-uniform -> s_loads)
template <int CO>
__global__ void k_conv1x1(const float* __restrict__ in, const float* __restrict__ wt,
                          const float* __restrict__ bias, float* __restrict__ out) {
  const int CG = CO / 16;
  int p = (blockIdx.x & 3) * 256 + threadIdx.x;
  int rest = blockIdx.x >> 2;
  int cg = rest % CG;
  int b = rest / CG;
  if (b >= NB) return;
  const float* ip = in + (size_t)b * NC * NTOK + p;
  const float* wp = wt + cg * 16 * NC;
  float acc[16];
#pragma unroll
  for (int i = 0; i < 16; i++) acc[i] = bias[cg * 16 + i];
  for (int ci = 0; ci < NC; ci++) {
    float mv = ip[ci * NTOK];
#pragma unroll
    for (int i = 0; i < 16; i++) acc[i] = fmaf(wp[i * NC + ci], mv, acc[i]);
  }
#pragma unroll
  for (int i = 0; i < 16; i++) out[((size_t)b * CO + cg * 16 + i) * NTOK + p] = acc[i];
}

// ---------------------------------------------------------------
// depthwise 3x3 pad=1 on (B,128,32,32)
__global__ void k_dw3(const float* __restrict__ in, const float* __restrict__ wt,
                      const float* __restrict__ bias, float* __restrict__ out) {
  int t = blockIdx.x * 256 + threadIdx.x;
  if (t >= NB * NC * NTOK) return;
  int p = t & 1023;
  int pw = p & 31, ph = p >> 5;
  int bc = t >> 10;
  int c = bc & 127;
  const float* ip = in + (size_t)bc * NTOK;
  const float* wp = wt + c * 9;
  float acc = bias[c];
#pragma unroll
  for (int ky = 0; ky < 3; ky++) {
    int ih = ph + ky - 1;
    if (ih < 0 || ih > 31) continue;
#pragma unroll
    for (int kx = 0; kx < 3; kx++) {
      int iw = pw + kx - 1;
      if (iw < 0 || iw > 31) continue;
      acc = fmaf(wp[ky * 3 + kx], ip[ih * 32 + iw], acc);
    }
  }
  out[t] = acc;
}

// ---------------------------------------------------------------
// grouped 3x3 (groups=128) on kv1 (B,256,32,32); emits bf16 K and bf16 V
__global__ void k_kv2(const float* __restrict__ in, const float* __restrict__ wt,
                      const float* __restrict__ bias, unsigned short* __restrict__ kbf,
                      unsigned short* __restrict__ vbf) {
  int t = blockIdx.x * 256 + threadIdx.x;
  if (t >= NB * 256 * NTOK) return;
  int p = t & 1023;
  int pw = p & 31, ph = p >> 5;
  int bo = t >> 10;
  int o = bo & 255;
  int b = bo >> 8;
  int g = o >> 1;
  const float* ip0 = in + ((size_t)b * 256 + 2 * g) * NTOK;
  const float* ip1 = ip0 + NTOK;
  const float* wp = wt + o * 18; // [2][3][3]
  float acc = bias[o];
#pragma unroll
  for (int ky = 0; ky < 3; ky++) {
    int ih = ph + ky - 1;
    if (ih < 0 || ih > 31) continue;
#pragma unroll
    for (int kx = 0; kx < 3; kx++) {
      int iw = pw + kx - 1;
      if (iw < 0 || iw > 31) continue;
      float w0 = wp[ky * 3 + kx];
      float w1 = wp[9 + ky * 3 + kx];
      acc = fmaf(w0, ip0[ih * 32 + iw], acc);
      acc = fmaf(w1, ip1[ih * 32 + iw], acc);
    }
  }
  unsigned short bv = (unsigned short)bf16r(acc);
  if (o < 128) {
    kbf[((size_t)b * NC + o) * NTOK + p] = bv;
  } else {
    int c = o - 128;
    int h = c >> 5, d = c & 31;
    vbf[(((size_t)b * HEADS + h) * NTOK + p) * HDIM + d] = bv;
  }
}

// ---------------------------------------------------------------
// attention v7: bsearch top-32 select with ALL per-row state statically
// indexed (2 rows per wave, fully interleaved/unrolled -> no scratch).
// grid: 2048 = 64 chunks x 4 h x 8 b; block 512 (8 waves), 2 rows per wave.
__launch_bounds__(512, 2)
__global__ void k_attn(const float* __restrict__ qbuf, const unsigned short* __restrict__ kbf,
                       const unsigned short* __restrict__ vbf, const float* __restrict__ rel,
                       const float* __restrict__ temp, float* __restrict__ att) {
  __shared__ __align__(16) unsigned ksh[16384];  // bf16 K [d][n], 64KB
  __shared__ __align__(16) unsigned cbuf[8 * 64]; // per-wave 32x(key,token), 2KB

  int bid = blockIdx.x;
  int chunk = bid & 63;
  int h = (bid >> 6) & 3;
  int b = bid >> 8;
  int tid = threadIdx.x;
  int lane = tid & 63;
  int wave = __builtin_amdgcn_readfirstlane(tid >> 6); // 0..7, uniform

  // stage K (already bf16 in global): 8192 uint2 total, 512 threads x 16
  const uint2* kg = (const uint2*)(kbf + ((size_t)b * NC + h * HDIM) * NTOK);
  uint2* kl = (uint2*)ksh;
#pragma unroll
  for (int i = 0; i < 16; i++) kl[tid + i * 512] = kg[tid + i * 512];
  __syncthreads();

  const float tmpr = temp[h];
  const float invt = 1.0f / tmpr;
  const uint2* k2 = (const uint2*)ksh;
  const unsigned short* vb = vbf + ((size_t)(b * HEADS + h)) * NTOK * HDIM;
  int vlane = lane & 31;
  unsigned* row_lds = cbuf + wave * 64; // 32 entries x 8B, private per wave

  int qbase = chunk * 16 + wave * 2;

  // acc init = rel * (1/t)
  v2f acc2[2][8];
  {
    const float4* relp = (const float4*)(rel + (((size_t)b * HEADS + h) * NTOK + qbase) * NTOK);
#pragma unroll
    for (int r = 0; r < 2; r++) {
#pragma unroll
      for (int i = 0; i < 4; i++) {
        float4 rv = relp[r * 256 + i * 64 + lane];
        v2f a0; a0.x = rv.x * invt; a0.y = rv.y * invt;
        v2f a1; a1.x = rv.z * invt; a1.y = rv.w * invt;
        acc2[r][i * 2 + 0] = a0;
        acc2[r][i * 2 + 1] = a1;
      }
    }
  }

  // logits: acc += q_d * K[d][j]
  const float* q0 = qbuf + ((size_t)b * NC + h * HDIM) * NTOK + qbase;
#pragma unroll 4
  for (int d = 0; d < 32; d++) {
    float2 qv = *(const float2*)&q0[d * NTOK];
#pragma unroll
    for (int i = 0; i < 4; i++) {
      uint2 kw = k2[d * 256 + i * 64 + lane];
      v2f klo = bfpair(kw.x);
      v2f khi = bfpair(kw.y);
      v2f q0s = {qv.x, qv.x}, q1s = {qv.y, qv.y};
      acc2[0][i * 2 + 0] = __builtin_elementwise_fma(q0s, klo, acc2[0][i * 2 + 0]);
      acc2[0][i * 2 + 1] = __builtin_elementwise_fma(q0s, khi, acc2[0][i * 2 + 1]);
      acc2[1][i * 2 + 0] = __builtin_elementwise_fma(q1s, klo, acc2[1][i * 2 + 0]);
      acc2[1][i * 2 + 1] = __builtin_elementwise_fma(q1s, khi, acc2[1][i * 2 + 1]);
    }
  }

  // full-precision monotone keys, statically indexed
  unsigned kk[2][16];
#pragma unroll
  for (int r = 0; r < 2; r++) {
#pragma unroll
    for (int j = 0; j < 8; j++) {
      kk[r][2 * j + 0] = fmap(tmpr * acc2[r][j].x);
      kk[r][2 * j + 1] = fmap(tmpr * acc2[r][j].y);
    }
  }

  // wave max per row (bsearch upper bound + softmax max)
  unsigned M[2];
#pragma unroll
  for (int r = 0; r < 2; r++) {
    unsigned mx = kk[r][0];
#pragma unroll
    for (int e = 1; e < 16; e++) mx = mx > kk[r][e] ? mx : kk[r][e];
    M[r] = wave_maxu(mx);
  }

  // interleaved binary search: smallest T with count(key > T) < 32
  unsigned lo0 = 0u, hi0 = M[0], lo1 = 0u, hi1 = M[1];
#pragma unroll 1
  for (int it = 0; it < 32; it++) {
    unsigned mid0 = lo0 + ((hi0 - lo0) >> 1);
    unsigned mid1 = lo1 + ((hi1 - lo1) >> 1);
    int c0 = 0, c1 = 0;
#pragma unroll
    for (int e = 0; e < 16; e++) {
      c0 += (int)__popcll(__ballot(kk[0][e] > mid0));
      c1 += (int)__popcll(__ballot(kk[1][e] > mid1));
    }
    if (c0 >= TOPK) lo0 = mid0; else hi0 = mid0;
    if (c1 >= TOPK) lo1 = mid1; else hi1 = mid1;
  }
  unsigned T[2] = {hi0, hi1};

  // per-row: tie handling, compaction, softmax + V gather (r unrolled -> static)
#pragma unroll
  for (int r = 0; r < 2; r++) {
    unsigned gtc = 0, tq = 0;
#pragma unroll
    for (int e = 0; e < 16; e++) {
      gtc += (kk[r][e] > T[r]) ? 1u : 0u;
      tq += (kk[r][e] == T[r]) ? 1u : 0u;
    }
    unsigned packed = gtc | (tq << 16);
    unsigned incl = wave_iprefix(packed, lane);
    unsigned tot = (unsigned)__builtin_amdgcn_readlane((int)incl, 63);
    unsigned n_gt = tot & 0xFFFFu;
    unsigned tie_pfx = (incl >> 16) - tq;
    unsigned extras = (unsigned)TOPK - n_gt; // >= 1 by construction
    int el = (int)extras - (int)tie_pfx;
    el = el < 0 ? 0 : el;
    el = el > (int)tq ? (int)tq : el;
    unsigned sc = gtc + (unsigned)el;
    unsigned wbase = wave_iprefix(sc, lane) - sc;

    unsigned wp = wbase, tr = tie_pfx;
#pragma unroll
    for (int e = 0; e < 16; e++) {
      bool gt = kk[r][e] > T[r];
      bool eq = (kk[r][e] == T[r]);
      bool take = gt || (eq && (tr < extras));
      tr += eq ? 1u : 0u;
      if (take) {
        ((uint2*)row_lds)[wp] = make_uint2(kk[r][e], (unsigned)((e >> 2) * 256 + lane * 4 + (e & 3)));
        wp++;
      }
    }

    // parallel softmax over the 32 entries (lanes 0..31) + pipelined V gather
    uint2 ent = ((const uint2*)row_lds)[vlane];
    float fv = funmap(ent.x);
    float mv = funmap(M[r]);
    float e_ = __expf(fv - mv);
    e_ = (lane < TOPK) ? e_ : 0.f;
    float se = wave_sumf(e_);

    float oacc = 0.f;
#pragma unroll
    for (int t = 0; t < TOPK; t++) {
      float es = __int_as_float(__builtin_amdgcn_readlane(__float_as_int(e_), t));
      int tok = __builtin_amdgcn_readlane((int)ent.y, t);
      float vv = __uint_as_float((unsigned)vb[(size_t)tok * HDIM + vlane] << 16);
      oacc = fmaf(es, vv, oacc);
    }

    if (lane < HDIM) {
      att[((size_t)b * NC + h * HDIM + lane) * NTOK + (qbase + r)] = oacc / se;
    }
  }
}

// ---------------------------------------------------------------
// bilinear 2x upsample weights (jax scale_and_translate semantics)
__device__ __forceinline__ void bil(int i, int& j0, int& j1, float& wa, float& wb) {
  if (i & 1) {
    j0 = i >> 1; j1 = j0 + 1; wa = 0.75f; wb = 0.25f;
    if (j1 > 31) { j1 = 31; wa = 1.f; wb = 0.f; }
  } else {
    j0 = (i >> 1) - 1; j1 = j0 + 1; wa = 0.25f; wb = 0.75f;
    if (j0 < 0) { j0 = 0; wa = 0.f; wb = 1.f; }
  }
}

// mid = lepe(x) + upsample(att) ; (B,128,64,64)
__global__ void k_mid(const float* __restrict__ x, const float* __restrict__ lepe_w,
                      const float* __restrict__ lepe_b, const float* __restrict__ att,
                      float* __restrict__ mid) {
  int t = blockIdx.x * 256 + threadIdx.x;
  if (t >= NB * NC * NH * NW) return;
  int w = t & 63;
  int h0 = (t >> 6) & 63;
  int bc = t >> 12;
  int c = bc & 127;
  const float* xp = x + (size_t)bc * (NH * NW);
  const float* wp = lepe_w + c * 25;
  float acc = lepe_b[c];
#pragma unroll
  for (int ky = 0; ky < 5; ky++) {
    int ih = h0 + ky - 2;
    if (ih < 0 || ih > 63) continue;
#pragma unroll
    for (int kx = 0; kx < 5; kx++) {
      int iw = w + kx - 2;
      if (iw < 0 || iw > 63) continue;
      acc = fmaf(wp[ky * 5 + kx], xp[ih * 64 + iw], acc);
    }
  }
  int jh0, jh1, jw0, jw1;
  float wha, whb, wwa, wwb;
  bil(h0, jh0, jh1, wha, whb);
  bil(w, jw0, jw1, wwa, wwb);
  const float* ap = att + (size_t)bc * NTOK;
  float up = wha * (wwa * ap[jh0 * 32 + jw0] + wwb * ap[jh0 * 32 + jw1]) +
             whb * (wwa * ap[jh1 * 32 + jw0] + wwb * ap[jh1 * 32 + jw1]);
  mid[t] = acc + up;
}

// ---------------------------------------------------------------
// final 1x1 conv, 32 outputs per thread (mid re-read 4x instead of 16x)
__global__ void k_final(const float* __restrict__ mid, const float* __restrict__ wt,
                        const float* __restrict__ bias, float* __restrict__ out) {
  int p = (blockIdx.x & 15) * 256 + threadIdx.x;
  int rest = blockIdx.x >> 4;
  int cg = rest & 3;
  int b = rest >> 2;
  if (b >= NB) return;
  const float* mp = mid + (size_t)b * NC * (NH * NW) + p;
  const float* wp = wt + cg * 32 * NC;
  float acc[32];
#pragma unroll
  for (int i = 0; i < 32; i++) acc[i] = bias[cg * 32 + i];
  for (int ci = 0; ci < NC; ci++) {
    float mv = mp[ci * 4096];
#pragma unroll
    for (int i = 0; i < 32; i++) acc[i] = fmaf(wp[i * NC + ci], mv, acc[i]);
  }
#pragma unroll
  for (int i = 0; i < 32; i++) out[((size_t)b * NC + cg * 32 + i) * 4096 + p] = acc[i];
}

// ---------------------------------------------------------------
extern "C" void kernel_launch(void* const* d_in, const int* in_sizes, int n_in,
                              void* d_out, int out_size, void* d_ws, size_t ws_size,
                              hipStream_t stream) {
  const float* x      = (const float*)d_in[0];
  const float* y      = (const float*)d_in[1];
  const float* rel    = (const float*)d_in[2];
  const float* q1_w   = (const float*)d_in[3];
  const float* q1_b   = (const float*)d_in[4];
  const float* q2_w   = (const float*)d_in[5];
  const float* q2_b   = (const float*)d_in[6];
  const float* kv1_w  = (const float*)d_in[7];
  const float* kv1_b  = (const float*)d_in[8];
  const float* kv2_w  = (const float*)d_in[9];
  const float* kv2_b  = (const float*)d_in[10];
  const float* lepe_w = (const float*)d_in[11];
  const float* lepe_b = (const float*)d_in[12];
  const float* out_w  = (const float*)d_in[13];
  const float* out_b  = (const float*)d_in[14];
  const float* temp   = (const float*)d_in[15];
  float* out = (float*)d_out;

  float* ws = (float*)d_ws;
  const size_t SP = (size_t)NB * NC * NTOK;   // 1,048,576
  float* xp     = ws;                  // SP
  float* yp     = xp + SP;             // SP
  float* q1buf  = yp + SP;             // SP
  float* kv1buf = q1buf + SP;          // 2*SP
  float* qbuf   = kv1buf + 2 * SP;     // SP
  float* attb   = qbuf + SP;           // SP
  float* mid    = attb + SP;           // 4*SP
  unsigned short* kbf = (unsigned short*)(mid + 4 * SP);  // SP ushorts (2MB)
  unsigned short* vbf = kbf + SP;                         // SP ushorts (2MB)

  k_pool<<<8192, 256, 0, stream>>>(x, y, xp, yp);
  k_conv1x1<128><<<256, 256, 0, stream>>>(xp, q1_w, q1_b, q1buf);
  k_dw3<<<4096, 256, 0, stream>>>(q1buf, q2_w, q2_b, qbuf);
  k_conv1x1<256><<<512, 256, 0, stream>>>(yp, kv1_w, kv1_b, kv1buf);
  k_kv2<<<8192, 256, 0, stream>>>(kv1buf, kv2_w, kv2_b, kbf, vbf);
  k_attn<<<2048, 512, 0, stream>>>(qbuf, kbf, vbf, rel, temp, attb);
  k_mid<<<16384, 256, 0, stream>>>(x, lepe_w, lepe_b, attb, mid);
  k_final<<<512, 256, 0, stream>>>(mid, out_w, out_b, out);
}

// Round 11
// 250.361 us; speedup vs baseline: 1.3736x; 1.1940x over previous
//
#include <hip/hip_runtime.h>

// Problem constants
#define NB 8
#define NC 128
#define NH 64
#define NW 64
#define HEADS 4
#define HP 32
#define WP 32
#define NTOK 1024     // HP*WP
#define TOPK 32
#define HDIM 32

typedef float v2f __attribute__((ext_vector_type(2)));

// ---------------------------------------------------------------
// bf16 helpers (round-to-nearest-even)
__device__ __forceinline__ unsigned bf16r(float f) {
  unsigned u = __float_as_uint(f);
  return (u + 0x7FFFu + ((u >> 16) & 1u)) >> 16;
}

// monotone float->uint map (order-preserving) and inverse
__device__ __forceinline__ unsigned fmap(float f) {
  unsigned u = __float_as_uint(f);
  return u ^ ((unsigned)((int)u >> 31) | 0x80000000u);
}
__device__ __forceinline__ float funmap(unsigned k) {
  unsigned uo = k ^ ((unsigned)((int)(~k) >> 31) | 0x80000000u);
  return __uint_as_float(uo);
}

__device__ __forceinline__ v2f bfpair(unsigned w) {
  v2f r;
  r.x = __uint_as_float(w << 16);
  r.y = __uint_as_float(w & 0xFFFF0000u);
  return r;
}

// DPP wave64 max-reduce on unsigned; result broadcast via readlane(63)
__device__ __forceinline__ unsigned wave_maxu(unsigned v) {
#define ST(ctrl)                                                                     \
  {                                                                                  \
    unsigned o = (unsigned)__builtin_amdgcn_update_dpp(0, (int)v, ctrl, 0xF, 0xF, true); \
    v = v > o ? v : o;                                                               \
  }
  ST(0xB1)   // quad_perm [1,0,3,2]
  ST(0x4E)   // quad_perm [2,3,0,1]
  ST(0x141)  // row_half_mirror
  ST(0x140)  // row_mirror
  ST(0x142)  // row_bcast:15
  ST(0x143)  // row_bcast:31
#undef ST
  return (unsigned)__builtin_amdgcn_readlane((int)v, 63);
}

// DPP wave64 float sum-reduce; result broadcast via readlane(63)
__device__ __forceinline__ float wave_sumf(float v) {
#define STA(ctrl)                                                                    \
  v += __int_as_float(__builtin_amdgcn_update_dpp(0, __float_as_int(v), ctrl, 0xF, 0xF, true));
  STA(0xB1)
  STA(0x4E)
  STA(0x141)
  STA(0x140)
  STA(0x142)
  STA(0x143)
#undef STA
  return __int_as_float(__builtin_amdgcn_readlane(__float_as_int(v), 63));
}

// DPP wave64 inclusive prefix-sum on unsigned. Safe for packed 16+16 fields.
__device__ __forceinline__ unsigned wave_iprefix(unsigned v, int lane) {
#define SH(ctrl)                                                                     \
  v += (unsigned)__builtin_amdgcn_update_dpp(0, (int)v, ctrl, 0xF, 0xF, true);
  SH(0x111)  // row_shr:1
  SH(0x112)  // row_shr:2
  SH(0x114)  // row_shr:4
  SH(0x118)  // row_shr:8
#undef SH
  unsigned r0 = (unsigned)__builtin_amdgcn_readlane((int)v, 15);
  unsigned r1 = (unsigned)__builtin_amdgcn_readlane((int)v, 31);
  unsigned r2 = (unsigned)__builtin_amdgcn_readlane((int)v, 47);
  v += (lane >= 16) ? r0 : 0u;
  v += (lane >= 32) ? r1 : 0u;
  v += (lane >= 48) ? r2 : 0u;
  return v;
}

// ---------------------------------------------------------------
// avg pool 2x2 on x and y
__global__ void k_pool(const float* __restrict__ x, const float* __restrict__ y,
                       float* __restrict__ xp, float* __restrict__ yp) {
  int idx = blockIdx.x * 256 + threadIdx.x;
  const int total = NB * NC * HP * WP; // 1,048,576
  if (idx >= 2 * total) return;
  bool isY = idx >= total;
  int i = isY ? idx - total : idx;
  int pw = i & 31, ph = (i >> 5) & 31, bc = i >> 10;
  const float* src = (isY ? y : x) + ((size_t)bc * 64 + ph * 2) * 64 + pw * 2;
  float v = 0.25f * (src[0] + src[1] + src[64] + src[65]);
  (isY ? yp : xp)[i] = v;
}

// ---------------------------------------------------------------
// fused q path: 1x1 conv (4 ch/thread, wave-uniform weights) -> LDS tile ->
// depthwise 3x3. block = 1024 threads (one 32x32 image), grid = 8b x 32 quads.
__launch_bounds__(1024, 2)
__global__ void k_qpath(const float* __restrict__ xp, const float* __restrict__ w1,
                        const float* __restrict__ b1, const float* __restrict__ w2,
                        const float* __restrict__ b2, float* __restrict__ qbuf) {
  __shared__ float cls[4][1024];
  int px = threadIdx.x;
  int q = blockIdx.x & 31;   // channel quad (4 channels)
  int b = blockIdx.x >> 5;
  const float* ip = xp + (size_t)b * NC * NTOK + px;
  const float* wp = w1 + q * 4 * NC;
  float acc[4];
#pragma unroll
  for (int i = 0; i < 4; i++) acc[i] = b1[q * 4 + i];
  for (int ci = 0; ci < NC; ci++) {
    float mv = ip[ci * NTOK];
#pragma unroll
    for (int i = 0; i < 4; i++) acc[i] = fmaf(wp[i * NC + ci], mv, acc[i]);
  }
#pragma unroll
  for (int i = 0; i < 4; i++) cls[i][px] = acc[i];
  __syncthreads();
  int pw = px & 31, ph = px >> 5;
#pragma unroll
  for (int i = 0; i < 4; i++) {
    int c = q * 4 + i;
    const float* wq = w2 + c * 9;
    float a = b2[c];
#pragma unroll
    for (int ky = 0; ky < 3; ky++) {
      int ih = ph + ky - 1;
      if (ih < 0 || ih > 31) continue;
#pragma unroll
      for (int kx = 0; kx < 3; kx++) {
        int iw = pw + kx - 1;
        if (iw < 0 || iw > 31) continue;
        a = fmaf(wq[ky * 3 + kx], cls[i][ih * 32 + iw], a);
      }
    }
    qbuf[((size_t)b * NC + c) * NTOK + px] = a;
  }
}

// ---------------------------------------------------------------
// fused kv path: 1x1 conv (4 ch/thread) -> LDS tile -> grouped 3x3 (2-ch
// groups are self-contained in a 4-ch quad) -> bf16 K / bf16 V.
// block = 1024 threads, grid = 8b x 64 quads.
__launch_bounds__(1024, 2)
__global__ void k_kvpath(const float* __restrict__ yp, const float* __restrict__ w1,
                         const float* __restrict__ b1, const float* __restrict__ w2,
                         const float* __restrict__ b2, unsigned short* __restrict__ kbf,
                         unsigned short* __restrict__ vbf) {
  __shared__ float cls[4][1024];
  int px = threadIdx.x;
  int q = blockIdx.x & 63;   // channel quad of the 256 kv1 channels
  int b = blockIdx.x >> 6;
  const float* ip = yp + (size_t)b * NC * NTOK + px;
  const float* wp = w1 + q * 4 * NC;
  float acc[4];
#pragma unroll
  for (int i = 0; i < 4; i++) acc[i] = b1[q * 4 + i];
  for (int ci = 0; ci < NC; ci++) {
    float mv = ip[ci * NTOK];
#pragma unroll
    for (int i = 0; i < 4; i++) acc[i] = fmaf(wp[i * NC + ci], mv, acc[i]);
  }
#pragma unroll
  for (int i = 0; i < 4; i++) cls[i][px] = acc[i];
  __syncthreads();
  int pw = px & 31, ph = px >> 5;
#pragma unroll
  for (int i = 0; i < 4; i++) {
    int o = q * 4 + i;       // kv1/kv2 channel 0..255
    int l0 = i & ~1;         // local index of the group's first input channel
    const float* wq = w2 + o * 18; // [2][3][3]
    float a = b2[o];
#pragma unroll
    for (int ky = 0; ky < 3; ky++) {
      int ih = ph + ky - 1;
      if (ih < 0 || ih > 31) continue;
#pragma unroll
      for (int kx = 0; kx < 3; kx++) {
        int iw = pw + kx - 1;
        if (iw < 0 || iw > 31) continue;
        a = fmaf(wq[ky * 3 + kx], cls[l0][ih * 32 + iw], a);
        a = fmaf(wq[9 + ky * 3 + kx], cls[l0 + 1][ih * 32 + iw], a);
      }
    }
    unsigned short bv = (unsigned short)bf16r(a);
    if (o < 128) {
      kbf[((size_t)b * NC + o) * NTOK + px] = bv;
    } else {
      int c = o - 128;
      int h = c >> 5, d = c & 31;
      vbf[(((size_t)b * HEADS + h) * NTOK + px) * HDIM + d] = bv;
    }
  }
}

// ---------------------------------------------------------------
// attention v8: early-exit bsearch top-32 (expected ~9 iters; cap 32 with
// exact-tie fallback), static indexing throughout.
// grid: 2048 = 64 chunks x 4 h x 8 b; block 512 (8 waves), 2 rows per wave.
__launch_bounds__(512, 2)
__global__ void k_attn(const float* __restrict__ qbuf, const unsigned short* __restrict__ kbf,
                       const unsigned short* __restrict__ vbf, const float* __restrict__ rel,
                       const float* __restrict__ temp, float* __restrict__ att) {
  __shared__ __align__(16) unsigned ksh[16384];  // bf16 K [d][n], 64KB
  __shared__ __align__(16) unsigned cbuf[8 * 64]; // per-wave 32x(key,token), 2KB

  int bid = blockIdx.x;
  int chunk = bid & 63;
  int h = (bid >> 6) & 3;
  int b = bid >> 8;
  int tid = threadIdx.x;
  int lane = tid & 63;
  int wave = __builtin_amdgcn_readfirstlane(tid >> 6); // 0..7, uniform

  // stage K (already bf16 in global): 8192 uint2 total, 512 threads x 16
  const uint2* kg = (const uint2*)(kbf + ((size_t)b * NC + h * HDIM) * NTOK);
  uint2* kl = (uint2*)ksh;
#pragma unroll
  for (int i = 0; i < 16; i++) kl[tid + i * 512] = kg[tid + i * 512];
  __syncthreads();

  const float tmpr = temp[h];
  const float invt = 1.0f / tmpr;
  const uint2* k2 = (const uint2*)ksh;
  const unsigned short* vb = vbf + ((size_t)(b * HEADS + h)) * NTOK * HDIM;
  int vlane = lane & 31;
  unsigned* row_lds = cbuf + wave * 64; // 32 entries x 8B, private per wave

  int qbase = chunk * 16 + wave * 2;

  // acc init = rel * (1/t)
  v2f acc2[2][8];
  {
    const float4* relp = (const float4*)(rel + (((size_t)b * HEADS + h) * NTOK + qbase) * NTOK);
#pragma unroll
    for (int r = 0; r < 2; r++) {
#pragma unroll
      for (int i = 0; i < 4; i++) {
        float4 rv = relp[r * 256 + i * 64 + lane];
        v2f a0; a0.x = rv.x * invt; a0.y = rv.y * invt;
        v2f a1; a1.x = rv.z * invt; a1.y = rv.w * invt;
        acc2[r][i * 2 + 0] = a0;
        acc2[r][i * 2 + 1] = a1;
      }
    }
  }

  // logits: acc += q_d * K[d][j]
  const float* q0 = qbuf + ((size_t)b * NC + h * HDIM) * NTOK + qbase;
#pragma unroll 4
  for (int d = 0; d < 32; d++) {
    float2 qv = *(const float2*)&q0[d * NTOK];
#pragma unroll
    for (int i = 0; i < 4; i++) {
      uint2 kw = k2[d * 256 + i * 64 + lane];
      v2f klo = bfpair(kw.x);
      v2f khi = bfpair(kw.y);
      v2f q0s = {qv.x, qv.x}, q1s = {qv.y, qv.y};
      acc2[0][i * 2 + 0] = __builtin_elementwise_fma(q0s, klo, acc2[0][i * 2 + 0]);
      acc2[0][i * 2 + 1] = __builtin_elementwise_fma(q0s, khi, acc2[0][i * 2 + 1]);
      acc2[1][i * 2 + 0] = __builtin_elementwise_fma(q1s, klo, acc2[1][i * 2 + 0]);
      acc2[1][i * 2 + 1] = __builtin_elementwise_fma(q1s, khi, acc2[1][i * 2 + 1]);
    }
  }

  // full-precision monotone keys, statically indexed
  unsigned kk[2][16];
#pragma unroll
  for (int r = 0; r < 2; r++) {
#pragma unroll
    for (int j = 0; j < 8; j++) {
      kk[r][2 * j + 0] = fmap(tmpr * acc2[r][j].x);
      kk[r][2 * j + 1] = fmap(tmpr * acc2[r][j].y);
    }
  }

  // wave max per row (bsearch upper bound + softmax max)
  unsigned M[2];
#pragma unroll
  for (int r = 0; r < 2; r++) {
    unsigned mx = kk[r][0];
#pragma unroll
    for (int e = 1; e < 16; e++) mx = mx > kk[r][e] ? mx : kk[r][e];
    M[r] = wave_maxu(mx);
  }

  // early-exit binary search: stop a row when count(key > mid) == 32 exactly
  // (then T=mid, zero ties needed). Cap 32 iters -> exact-tie fallback (T=hi,
  // reached only when straddling keys are bit-identical).
  unsigned lo0 = 0u, hi0 = M[0], lo1 = 0u, hi1 = M[1];
  unsigned T0x = 0u, T1x = 0u;
  bool d0 = false, d1 = false;
#pragma unroll 1
  for (int it = 0; it < 32; it++) {
    if (d0 && d1) break;
    if (!d0) {
      unsigned mid0 = lo0 + ((hi0 - lo0) >> 1);
      int c0 = 0;
#pragma unroll
      for (int e = 0; e < 16; e++) c0 += (int)__popcll(__ballot(kk[0][e] > mid0));
      if (c0 >= TOPK) lo0 = mid0; else hi0 = mid0;
      if (c0 == TOPK) { T0x = mid0; d0 = true; }
    }
    if (!d1) {
      unsigned mid1 = lo1 + ((hi1 - lo1) >> 1);
      int c1 = 0;
#pragma unroll
      for (int e = 0; e < 16; e++) c1 += (int)__popcll(__ballot(kk[1][e] > mid1));
      if (c1 >= TOPK) lo1 = mid1; else hi1 = mid1;
      if (c1 == TOPK) { T1x = mid1; d1 = true; }
    }
  }
  unsigned T[2];
  T[0] = d0 ? T0x : hi0;
  T[1] = d1 ? T1x : hi1;

  // per-row: tie handling, compaction, softmax + V gather (r unrolled -> static)
#pragma unroll
  for (int r = 0; r < 2; r++) {
    unsigned gtc = 0, tq = 0;
#pragma unroll
    for (int e = 0; e < 16; e++) {
      gtc += (kk[r][e] > T[r]) ? 1u : 0u;
      tq += (kk[r][e] == T[r]) ? 1u : 0u;
    }
    unsigned packed = gtc | (tq << 16);
    unsigned incl = wave_iprefix(packed, lane);
    unsigned tot = (unsigned)__builtin_amdgcn_readlane((int)incl, 63);
    unsigned n_gt = tot & 0xFFFFu;
    unsigned tie_pfx = (incl >> 16) - tq;
    unsigned extras = (unsigned)TOPK - n_gt; // 0 on early-exit rows
    int el = (int)extras - (int)tie_pfx;
    el = el < 0 ? 0 : el;
    el = el > (int)tq ? (int)tq : el;
    unsigned sc = gtc + (unsigned)el;
    unsigned wbase = wave_iprefix(sc, lane) - sc;

    unsigned wp = wbase, tr = tie_pfx;
#pragma unroll
    for (int e = 0; e < 16; e++) {
      bool gt = kk[r][e] > T[r];
      bool eq = (kk[r][e] == T[r]);
      bool take = gt || (eq && (tr < extras));
      tr += eq ? 1u : 0u;
      if (take) {
        ((uint2*)row_lds)[wp] = make_uint2(kk[r][e], (unsigned)((e >> 2) * 256 + lane * 4 + (e & 3)));
        wp++;
      }
    }

    // parallel softmax over the 32 entries (lanes 0..31) + pipelined V gather
    uint2 ent = ((const uint2*)row_lds)[vlane];
    float fv = funmap(ent.x);
    float mv = funmap(M[r]);
    float e_ = __expf(fv - mv);
    e_ = (lane < TOPK) ? e_ : 0.f;
    float se = wave_sumf(e_);

    float oacc = 0.f;
#pragma unroll
    for (int t = 0; t < TOPK; t++) {
      float es = __int_as_float(__builtin_amdgcn_readlane(__float_as_int(e_), t));
      int tok = __builtin_amdgcn_readlane((int)ent.y, t);
      float vv = __uint_as_float((unsigned)vb[(size_t)tok * HDIM + vlane] << 16);
      oacc = fmaf(es, vv, oacc);
    }

    if (lane < HDIM) {
      att[((size_t)b * NC + h * HDIM + lane) * NTOK + (qbase + r)] = oacc / se;
    }
  }
}

// ---------------------------------------------------------------
// bilinear 2x upsample weights (jax scale_and_translate semantics)
__device__ __forceinline__ void bil(int i, int& j0, int& j1, float& wa, float& wb) {
  if (i & 1) {
    j0 = i >> 1; j1 = j0 + 1; wa = 0.75f; wb = 0.25f;
    if (j1 > 31) { j1 = 31; wa = 1.f; wb = 0.f; }
  } else {
    j0 = (i >> 1) - 1; j1 = j0 + 1; wa = 0.25f; wb = 0.75f;
    if (j0 < 0) { j0 = 0; wa = 0.f; wb = 1.f; }
  }
}

// mid = lepe(x) + upsample(att) ; (B,128,64,64)
__global__ void k_mid(const float* __restrict__ x, const float* __restrict__ lepe_w,
                      const float* __restrict__ lepe_b, const float* __restrict__ att,
                      float* __restrict__ mid) {
  int t = blockIdx.x * 256 + threadIdx.x;
  if (t >= NB * NC * NH * NW) return;
  int w = t & 63;
  int h0 = (t >> 6) & 63;
  int bc = t >> 12;
  int c = bc & 127;
  const float* xp = x + (size_t)bc * (NH * NW);
  const float* wp = lepe_w + c * 25;
  float acc = lepe_b[c];
#pragma unroll
  for (int ky = 0; ky < 5; ky++) {
    int ih = h0 + ky - 2;
    if (ih < 0 || ih > 63) continue;
#pragma unroll
    for (int kx = 0; kx < 5; kx++) {
      int iw = w + kx - 2;
      if (iw < 0 || iw > 63) continue;
      acc = fmaf(wp[ky * 5 + kx], xp[ih * 64 + iw], acc);
    }
  }
  int jh0, jh1, jw0, jw1;
  float wha, whb, wwa, wwb;
  bil(h0, jh0, jh1, wha, whb);
  bil(w, jw0, jw1, wwa, wwb);
  const float* ap = att + (size_t)bc * NTOK;
  float up = wha * (wwa * ap[jh0 * 32 + jw0] + wwb * ap[jh0 * 32 + jw1]) +
             whb * (wwa * ap[jh1 * 32 + jw0] + wwb * ap[jh1 * 32 + jw1]);
  mid[t] = acc + up;
}

// ---------------------------------------------------------------
// final 1x1 conv, 32 outputs per thread (mid re-read 4x instead of 16x)
__global__ void k_final(const float* __restrict__ mid, const float* __restrict__ wt,
                        const float* __restrict__ bias, float* __restrict__ out) {
  int p = (blockIdx.x & 15) * 256 + threadIdx.x;
  int rest = blockIdx.x >> 4;
  int cg = rest & 3;
  int b = rest >> 2;
  if (b >= NB) return;
  const float* mp = mid + (size_t)b * NC * (NH * NW) + p;
  const float* wp = wt + cg * 32 * NC;
  float acc[32];
#pragma unroll
  for (int i = 0; i < 32; i++) acc[i] = bias[cg * 32 + i];
  for (int ci = 0; ci < NC; ci++) {
    float mv = mp[ci * 4096];
#pragma unroll
    for (int i = 0; i < 32; i++) acc[i] = fmaf(wp[i * NC + ci], mv, acc[i]);
  }
#pragma unroll
  for (int i = 0; i < 32; i++) out[((size_t)b * NC + cg * 32 + i) * 4096 + p] = acc[i];
}

// ---------------------------------------------------------------
extern "C" void kernel_launch(void* const* d_in, const int* in_sizes, int n_in,
                              void* d_out, int out_size, void* d_ws, size_t ws_size,
                              hipStream_t stream) {
  const float* x      = (const float*)d_in[0];
  const float* y      = (const float*)d_in[1];
  const float* rel    = (const float*)d_in[2];
  const float* q1_w   = (const float*)d_in[3];
  const float* q1_b   = (const float*)d_in[4];
  const float* q2_w   = (const float*)d_in[5];
  const float* q2_b   = (const float*)d_in[6];
  const float* kv1_w  = (const float*)d_in[7];
  const float* kv1_b  = (const float*)d_in[8];
  const float* kv2_w  = (const float*)d_in[9];
  const float* kv2_b  = (const float*)d_in[10];
  const float* lepe_w = (const float*)d_in[11];
  const float* lepe_b = (const float*)d_in[12];
  const float* out_w  = (const float*)d_in[13];
  const float* out_b  = (const float*)d_in[14];
  const float* temp   = (const float*)d_in[15];
  float* out = (float*)d_out;

  float* ws = (float*)d_ws;
  const size_t SP = (size_t)NB * NC * NTOK;   // 1,048,576
  float* xp     = ws;                  // SP
  float* yp     = xp + SP;             // SP
  float* qbuf   = yp + SP;             // SP
  float* attb   = qbuf + SP;           // SP
  float* mid    = attb + SP;           // 4*SP
  unsigned short* kbf = (unsigned short*)(mid + 4 * SP);  // SP ushorts (2MB)
  unsigned short* vbf = kbf + SP;                         // SP ushorts (2MB)

  k_pool<<<8192, 256, 0, stream>>>(x, y, xp, yp);
  k_qpath<<<256, 1024, 0, stream>>>(xp, q1_w, q1_b, q2_w, q2_b, qbuf);
  k_kvpath<<<512, 1024, 0, stream>>>(yp, kv1_w, kv1_b, kv2_w, kv2_b, kbf, vbf);
  k_attn<<<2048, 512, 0, stream>>>(qbuf, kbf, vbf, rel, temp, attb);
  k_mid<<<16384, 256, 0, stream>>>(x, lepe_w, lepe_b, attb, mid);
  k_final<<<512, 256, 0, stream>>>(mid, out_w, out_b, out);
}